// Round 1
// baseline (1453.562 us; speedup 1.0000x reference)
//
#include <hip/hip_runtime.h>
#include <hip/hip_bf16.h>

#define Bq 128
#define Tq 4096
#define Nq 32
#define LOG2E 1.4426950408889634f

// One exp-domain recursion step (forward): raw_new[j] = (sum_i s_i * eT[i][j]) * epot[j]
// Broadcast of the 32 state values via v_readlane -> SGPR; power-of-2 renormalization
// done on the SALU by subtracting e<<23 from the fp32 bit pattern.
__device__ __forceinline__ void step_fwd(float& raw, int& iscale, const float* eT, float epot) {
  int bits = __float_as_int(raw);
  int s0 = __builtin_amdgcn_readlane(bits, 0);
  int e = ((s0 >> 23) & 255) - 127;
  int sh = e << 23;
  iscale += e;
  float a0 = 0.f, a1 = 0.f, a2 = 0.f, a3 = 0.f;
#pragma unroll
  for (int i = 0; i < 32; i += 4) {
    a0 = fmaf(__int_as_float(__builtin_amdgcn_readlane(bits, i + 0) - sh), eT[i + 0], a0);
    a1 = fmaf(__int_as_float(__builtin_amdgcn_readlane(bits, i + 1) - sh), eT[i + 1], a1);
    a2 = fmaf(__int_as_float(__builtin_amdgcn_readlane(bits, i + 2) - sh), eT[i + 2], a2);
    a3 = fmaf(__int_as_float(__builtin_amdgcn_readlane(bits, i + 3) - sh), eT[i + 3], a3);
  }
  raw = ((a0 + a1) + (a2 + a3)) * epot;
}

// Backward step: w[j] = raw[j]*epot[j] first (per-lane), then raw_new[i] = sum_j s_j * eTrow[j]
__device__ __forceinline__ void step_bwd(float& raw, int& iscale, const float* eT, float epot) {
  float w = raw * epot;
  int bits = __float_as_int(w);
  int s0 = __builtin_amdgcn_readlane(bits, 0);
  int e = ((s0 >> 23) & 255) - 127;
  int sh = e << 23;
  iscale += e;
  float a0 = 0.f, a1 = 0.f, a2 = 0.f, a3 = 0.f;
#pragma unroll
  for (int i = 0; i < 32; i += 4) {
    a0 = fmaf(__int_as_float(__builtin_amdgcn_readlane(bits, i + 0) - sh), eT[i + 0], a0);
    a1 = fmaf(__int_as_float(__builtin_amdgcn_readlane(bits, i + 1) - sh), eT[i + 1], a1);
    a2 = fmaf(__int_as_float(__builtin_amdgcn_readlane(bits, i + 2) - sh), eT[i + 2], a2);
    a3 = fmaf(__int_as_float(__builtin_amdgcn_readlane(bits, i + 3) - sh), eT[i + 3], a3);
  }
  raw = (a0 + a1) + (a2 + a3);
}

// blocks 0..127: forward chain for batch b; blocks 128..255: backward chain for batch b-128.
extern "C" __global__ void __launch_bounds__(64)
crf_chain_kernel(const float* __restrict__ pot, const int* __restrict__ lengths,
                 const float* __restrict__ trans,
                 __hip_bfloat16* __restrict__ eaF, int* __restrict__ scF,
                 __hip_bfloat16* __restrict__ eaB, int* __restrict__ scB,
                 float* __restrict__ logZ) {
  const int lane = threadIdx.x;
  if (lane >= 32) return;
  const bool fwd = (blockIdx.x < Bq);
  const int b = fwd ? blockIdx.x : (blockIdx.x - Bq);
  const int len = lengths[b];
  const float* pb = pot + (size_t)b * Tq * Nq;
  const size_t base = (size_t)b * Tq;
  float eT[32];

  if (fwd) {
    // lane j holds exp2 of transitions column j (scaled to base-2)
#pragma unroll
    for (int i = 0; i < 32; ++i) eT[i] = exp2f(trans[i * Nq + lane] * LOG2E);

    float raw = exp2f(pb[lane] * LOG2E);  // alpha row 0 (exp domain, scale 0)
    int iscale = 0;
    eaF[(base + 0) * Nq + lane] = __float2bfloat16(raw);
    scF[base + 0] = 0;

    float pn[8];
    int t = 1;
#pragma unroll
    for (int k = 0; k < 8; ++k) { int tt = t + k; if (tt > Tq - 1) tt = Tq - 1; pn[k] = pb[tt * Nq + lane]; }
    while (t + 8 <= len) {
      float pc[8];
#pragma unroll
      for (int k = 0; k < 8; ++k) pc[k] = pn[k];
#pragma unroll
      for (int k = 0; k < 8; ++k) { int tt = t + 8 + k; if (tt > Tq - 1) tt = Tq - 1; pn[k] = pb[tt * Nq + lane]; }
#pragma unroll
      for (int k = 0; k < 8; ++k) {
        float epot = exp2f(pc[k] * LOG2E);
        step_fwd(raw, iscale, eT, epot);
        eaF[(base + t + k) * Nq + lane] = __float2bfloat16(raw);
        scF[base + t + k] = iscale;
      }
      t += 8;
    }
#pragma unroll
    for (int k = 0; k < 8; ++k) {
      if (t + k < len) {
        float epot = exp2f(pn[k] * LOG2E);
        step_fwd(raw, iscale, eT, epot);
        eaF[(base + t + k) * Nq + lane] = __float2bfloat16(raw);
        scF[base + t + k] = iscale;
      }
    }
    // logZ2 = log2(sum_j raw_j) + iscale
    float s = raw;
#pragma unroll
    for (int m = 1; m < 32; m <<= 1) s += __shfl_xor(s, m, 32);
    logZ[b] = log2f(s) + (float)iscale;
  } else {
    // lane i holds exp2 of transitions row i
#pragma unroll
    for (int j = 0; j < 32; ++j) eT[j] = exp2f(trans[lane * Nq + j] * LOG2E);

    float raw = 1.0f;  // beta at row len-1 is 0 in log domain
    int iscale = 0;
    eaB[(base + len - 1) * Nq + lane] = __float2bfloat16(1.0f);
    scB[base + len - 1] = 0;

    int rem = len - 1;  // number of backward steps
    int u = len - 1;    // next potential row to consume
    float pn[8];
#pragma unroll
    for (int k = 0; k < 8; ++k) { int tt = u - k; if (tt < 0) tt = 0; pn[k] = pb[tt * Nq + lane]; }
    while (rem >= 8) {
      float pc[8];
#pragma unroll
      for (int k = 0; k < 8; ++k) pc[k] = pn[k];
#pragma unroll
      for (int k = 0; k < 8; ++k) { int tt = u - 8 - k; if (tt < 0) tt = 0; pn[k] = pb[tt * Nq + lane]; }
#pragma unroll
      for (int k = 0; k < 8; ++k) {
        float epot = exp2f(pc[k] * LOG2E);
        step_bwd(raw, iscale, eT, epot);
        eaB[(base + u - k - 1) * Nq + lane] = __float2bfloat16(raw);
        scB[base + u - k - 1] = iscale;
      }
      u -= 8;
      rem -= 8;
    }
#pragma unroll
    for (int k = 0; k < 8; ++k) {
      if (k < rem) {
        float epot = exp2f(pn[k] * LOG2E);
        step_bwd(raw, iscale, eT, epot);
        eaB[(base + u - k - 1) * Nq + lane] = __float2bfloat16(raw);
        scB[base + u - k - 1] = iscale;
      }
    }
  }
}

// One block per batch: p[t][j] = eaF*eaB*2^(scF+scB-logZ2); dice from I and P sums.
extern "C" __global__ void __launch_bounds__(256)
dice_kernel(const __hip_bfloat16* __restrict__ eaF, const int* __restrict__ scF,
            const __hip_bfloat16* __restrict__ eaB, const int* __restrict__ scB,
            const float* __restrict__ logZ, const int* __restrict__ y,
            const int* __restrict__ lengths, float* __restrict__ out) {
  const int b = blockIdx.x;
  const int tid = threadIdx.x;
  const int lane = tid & 31;
  const int g = tid >> 5;  // 8 row-groups
  const int len = lengths[b];
  const float lz = logZ[b];
  const size_t base = (size_t)b * Tq;
  float I = 0.f, P = 0.f;
  for (int t = g; t < len; t += 8) {
    float af = __bfloat162float(eaF[(base + t) * Nq + lane]);
    float ab = __bfloat162float(eaB[(base + t) * Nq + lane]);
    float E = (float)(scF[base + t] + scB[base + t]) - lz;
    float p = af * ab * exp2f(E);
    P += p;
    if (lane == y[base + t]) I += p;
  }
#pragma unroll
  for (int m = 1; m < 32; m <<= 1) {
    I += __shfl_xor(I, m, 32);
    P += __shfl_xor(P, m, 32);
  }
  __shared__ float sI[8], sP[8];
  if (lane == 0) { sI[g] = I; sP[g] = P; }
  __syncthreads();
  if (tid == 0) {
    float It = 0.f, Pt = 0.f;
#pragma unroll
    for (int k = 0; k < 8; ++k) { It += sI[k]; Pt += sP[k]; }
    float dice = (2.f * It + 1.f) / ((float)len + Pt + 1.f);
    out[b] = 1.f - dice;
  }
}

extern "C" void kernel_launch(void* const* d_in, const int* in_sizes, int n_in,
                              void* d_out, int out_size, void* d_ws, size_t ws_size,
                              hipStream_t stream) {
  const float* pot = (const float*)d_in[0];
  const int* y_true = (const int*)d_in[1];
  const int* lengths = (const int*)d_in[2];
  const float* trans = (const float*)d_in[3];
  float* out = (float*)d_out;

  // workspace layout
  char* ws = (char*)d_ws;
  const size_t n_elems = (size_t)Bq * Tq * Nq;        // 16,777,216
  __hip_bfloat16* eaF = (__hip_bfloat16*)ws;          // 32 MiB
  __hip_bfloat16* eaB = (__hip_bfloat16*)(ws + n_elems * 2);  // 32 MiB
  int* scF = (int*)(ws + n_elems * 4);                // 2 MiB
  int* scB = (int*)(ws + n_elems * 4 + (size_t)Bq * Tq * 4);  // 2 MiB
  float* logZ = (float*)(ws + n_elems * 4 + (size_t)Bq * Tq * 8);

  crf_chain_kernel<<<2 * Bq, 64, 0, stream>>>(pot, lengths, trans, eaF, scF, eaB, scB, logZ);
  dice_kernel<<<Bq, 256, 0, stream>>>(eaF, scF, eaB, scB, logZ, y_true, lengths, out);
}

// Round 2
// 362.124 us; speedup vs baseline: 4.0140x; 4.0140x over previous
//
#include <hip/hip_runtime.h>
#include <hip/hip_bf16.h>

#define Bq 128
#define Tq 4096
#define Nq 32
#define SEGL 256
#define NSEG 16
#define BURN 48
#define LOG2E 1.4426950408889634f

// Scalar power-of-2 renorm: divide whole vector by 2^(exponent of lane0).
__device__ __forceinline__ void renorm(float& raw) {
  int s0 = __builtin_amdgcn_readfirstlane(__float_as_int(raw));
  int sh = s0 & 0x7f800000;
  float corr = __int_as_float(0x7f000000 - sh);  // 2^{-e}
  raw *= corr;
}

// Forward: raw_new[j] = (sum_i raw_i * eT[i][j]) * epot[j].  eT[i] = col of M in lane j.
__device__ __forceinline__ void step_fwd(float& raw, const float* eT, float epot) {
  int bits = __float_as_int(raw);
  float a0 = 0.f, a1 = 0.f, a2 = 0.f, a3 = 0.f;
#pragma unroll
  for (int i = 0; i < 32; i += 4) {
    a0 = fmaf(__int_as_float(__builtin_amdgcn_readlane(bits, i + 0)), eT[i + 0], a0);
    a1 = fmaf(__int_as_float(__builtin_amdgcn_readlane(bits, i + 1)), eT[i + 1], a1);
    a2 = fmaf(__int_as_float(__builtin_amdgcn_readlane(bits, i + 2)), eT[i + 2], a2);
    a3 = fmaf(__int_as_float(__builtin_amdgcn_readlane(bits, i + 3)), eT[i + 3], a3);
  }
  raw = ((a0 + a1) + (a2 + a3)) * epot;
}

// Backward: w[j] = raw[j]*epot[j]; raw_new[i] = sum_j w_j * eT[j].  eT[j] = row of M in lane i.
__device__ __forceinline__ void step_bwd(float& raw, const float* eT, float epot) {
  float w = raw * epot;
  int bits = __float_as_int(w);
  float a0 = 0.f, a1 = 0.f, a2 = 0.f, a3 = 0.f;
#pragma unroll
  for (int i = 0; i < 32; i += 4) {
    a0 = fmaf(__int_as_float(__builtin_amdgcn_readlane(bits, i + 0)), eT[i + 0], a0);
    a1 = fmaf(__int_as_float(__builtin_amdgcn_readlane(bits, i + 1)), eT[i + 1], a1);
    a2 = fmaf(__int_as_float(__builtin_amdgcn_readlane(bits, i + 2)), eT[i + 2], a2);
    a3 = fmaf(__int_as_float(__builtin_amdgcn_readlane(bits, i + 3)), eT[i + 3], a3);
  }
  raw = (a0 + a1) + (a2 + a3);
}

// grid = Bq*32 blocks of 64 threads. bid>>5 = batch; (bid&31): 0..15 fwd seg, 16..31 bwd seg.
// Segmented scan: each segment runs BURN warm-up steps (Hilbert contraction ~0.38/step
// makes the start-vector error ~1e-20 after 48 steps), then writes its SEGL rows.
extern "C" __global__ void __launch_bounds__(64)
crf_chain_kernel(const float* __restrict__ pot, const int* __restrict__ lengths,
                 const float* __restrict__ trans,
                 __hip_bfloat16* __restrict__ eaF, __hip_bfloat16* __restrict__ eaB) {
  const int lane = threadIdx.x;
  if (lane >= 32) return;
  const int bid = blockIdx.x;
  const int b = bid >> 5;
  const int r = bid & 31;
  const bool fwd = (r < NSEG);
  const int s = fwd ? r : r - NSEG;
  const int len = lengths[b];
  const int sL = s * SEGL;
  if (sL >= len) return;
  const float* pb = pot + (size_t)b * Tq * Nq;
  const size_t base = (size_t)b * Tq;
  float eT[32];

  if (fwd) {
#pragma unroll
    for (int i = 0; i < 32; ++i) eT[i] = exp2f(trans[i * Nq + lane] * LOG2E);

    const int tend = min(sL + SEGL, len);        // exclusive write bound
    const int tstart = (s == 0) ? 0 : sL - BURN; // held index at init
    float raw = exp2f(pb[tstart * Nq + lane] * LOG2E);
    if (tstart >= sL) eaF[(base + tstart) * Nq + lane] = __float2bfloat16(raw);

    int t = tstart + 1;
    float pn[4];
#pragma unroll
    for (int k = 0; k < 4; ++k) { int tt = t + k; if (tt > Tq - 1) tt = Tq - 1; pn[k] = pb[tt * Nq + lane]; }
    while (t + 4 <= tend) {
      float pc[4];
#pragma unroll
      for (int k = 0; k < 4; ++k) pc[k] = pn[k];
#pragma unroll
      for (int k = 0; k < 4; ++k) { int tt = t + 4 + k; if (tt > Tq - 1) tt = Tq - 1; pn[k] = pb[tt * Nq + lane]; }
      renorm(raw);
#pragma unroll
      for (int k = 0; k < 4; ++k) {
        step_fwd(raw, eT, exp2f(pc[k] * LOG2E));
        if (t + k >= sL) eaF[(base + t + k) * Nq + lane] = __float2bfloat16(raw);
      }
      t += 4;
    }
    renorm(raw);
#pragma unroll
    for (int k = 0; k < 4; ++k) {
      if (t + k < tend) {
        step_fwd(raw, eT, exp2f(pn[k] * LOG2E));
        if (t + k >= sL) eaF[(base + t + k) * Nq + lane] = __float2bfloat16(raw);
      }
    }
  } else {
#pragma unroll
    for (int j = 0; j < 32; ++j) eT[j] = exp2f(trans[lane * Nq + j] * LOG2E);

    const int end = min(sL + SEGL, len) - 1;     // inclusive last write index
    const int t1 = min(len - 1, end + BURN);     // start index (beta = ones)
    float raw = 1.0f;
    if (t1 <= end) eaB[(base + t1) * Nq + lane] = __float2bfloat16(raw);

    int u = t1;  // consume pot row u to produce beta_{u-1}
    float pn[4];
#pragma unroll
    for (int k = 0; k < 4; ++k) { int tt = u - k; if (tt < 0) tt = 0; pn[k] = pb[tt * Nq + lane]; }
    while (u - 4 >= sL) {
      float pc[4];
#pragma unroll
      for (int k = 0; k < 4; ++k) pc[k] = pn[k];
#pragma unroll
      for (int k = 0; k < 4; ++k) { int tt = u - 4 - k; if (tt < 0) tt = 0; pn[k] = pb[tt * Nq + lane]; }
      renorm(raw);
#pragma unroll
      for (int k = 0; k < 4; ++k) {
        step_bwd(raw, eT, exp2f(pc[k] * LOG2E));
        int tw = u - 1 - k;
        if (tw <= end) eaB[(base + tw) * Nq + lane] = __float2bfloat16(raw);
      }
      u -= 4;
    }
    renorm(raw);
    const int rem = u - sL;  // 0..3 steps remain
#pragma unroll
    for (int k = 0; k < 4; ++k) {
      if (k < rem) {
        step_bwd(raw, eT, exp2f(pn[k] * LOG2E));
        int tw = u - 1 - k;
        if (tw <= end) eaB[(base + tw) * Nq + lane] = __float2bfloat16(raw);
      }
    }
  }
}

// One block per batch, 1024 threads = 32 row-groups of 32 lanes.
// p_t = a*b / sum_j(a*b) per position; I = sum p_t[y_t]; sum_j p_t[j] == 1 so P == len.
extern "C" __global__ void __launch_bounds__(1024)
dice_kernel(const __hip_bfloat16* __restrict__ eaF, const __hip_bfloat16* __restrict__ eaB,
            const int* __restrict__ y, const int* __restrict__ lengths,
            float* __restrict__ out) {
  const int b = blockIdx.x;
  const int tid = threadIdx.x;
  const int lane = tid & 31;
  const int g = tid >> 5;  // 32 row-groups
  const int len = lengths[b];
  const size_t base = (size_t)b * Tq;
  float I = 0.f;
  for (int t = g; t < len; t += 32) {
    float af = __bfloat162float(eaF[(base + t) * Nq + lane]);
    float ab = __bfloat162float(eaB[(base + t) * Nq + lane]);
    float v = af * ab;
    int yt = y[base + t];
    float py = (lane == yt) ? v : 0.f;
#pragma unroll
    for (int m = 1; m < 32; m <<= 1) {
      v += __shfl_xor(v, m, 32);
      py += __shfl_xor(py, m, 32);
    }
    I += py / v;
  }
  __shared__ float sI[32];
  if (lane == 0) sI[g] = I;
  __syncthreads();
  if (tid == 0) {
    float It = 0.f;
#pragma unroll
    for (int k = 0; k < 32; ++k) It += sI[k];
    float dice = (2.f * It + 1.f) / (2.f * (float)len + 1.f);
    out[b] = 1.f - dice;
  }
}

extern "C" void kernel_launch(void* const* d_in, const int* in_sizes, int n_in,
                              void* d_out, int out_size, void* d_ws, size_t ws_size,
                              hipStream_t stream) {
  const float* pot = (const float*)d_in[0];
  const int* y_true = (const int*)d_in[1];
  const int* lengths = (const int*)d_in[2];
  const float* trans = (const float*)d_in[3];
  float* out = (float*)d_out;

  char* ws = (char*)d_ws;
  const size_t n_elems = (size_t)Bq * Tq * Nq;               // 16,777,216
  __hip_bfloat16* eaF = (__hip_bfloat16*)ws;                 // 32 MiB
  __hip_bfloat16* eaB = (__hip_bfloat16*)(ws + n_elems * 2); // 32 MiB

  crf_chain_kernel<<<Bq * 32, 64, 0, stream>>>(pot, lengths, trans, eaF, eaB);
  dice_kernel<<<Bq, 1024, 0, stream>>>(eaF, eaB, y_true, lengths, out);
}

// Round 3
// 173.270 us; speedup vs baseline: 8.3890x; 2.0899x over previous
//
#include <hip/hip_runtime.h>
#include <hip/hip_bf16.h>

#define Bq 128
#define Tq 4096
#define Nq 32
#define SEGL 128
#define NSEG 32          // Tq / SEGL
#define BURN 25
#define TRIPB 24         // burn steps (BURN-1)
#define TRIP 152         // TRIPB + SEGL
#define UNR 8
#define NBLK 19          // TRIP / UNR
#define LOG2E 1.4426950408889634f

typedef float v2f __attribute__((ext_vector_type(2)));
typedef float v4f __attribute__((ext_vector_type(4)));
typedef unsigned short u16;

__device__ __forceinline__ u16 f2bf(float f) {  // RNE f32->bf16
  unsigned u = __float_as_uint(f);
  u = u + 0x7fffu + ((u >> 16) & 1u);
  return (u16)(u >> 16);
}

// One wave per (batch b, segment s): lanes 0-31 run the forward chain, lanes
// 32-63 the backward chain. Broadcast of the 32-state vector goes through LDS
// (1 ds_write_b32 + 8 ds_read_b128, 2-way bank alias = free). A single uniform
// 152-step loop covers burn-in + main; per-lane `skip` keeps raw at its init
// until the chain's real first step, and the store window [wlo,whi] masks
// exactly the rows this segment owns (init rows fall out automatically).
// Rows are stored bf16 with arbitrary per-row power-of-2 scale; dice
// renormalizes per row, so no scale arrays and no logZ are needed.
extern "C" __global__ void __launch_bounds__(64, 4)
crf_chain_kernel(const float* __restrict__ pot, const int* __restrict__ lengths,
                 const float* __restrict__ trans,
                 u16* __restrict__ eaF, u16* __restrict__ eaB) {
  __shared__ v4f sbuf4[16];
  float* sbuf = (float*)sbuf4;
  const int tid = threadIdx.x;
  const int j = tid & 31;
  const int half = tid >> 5;           // 0 = fwd, 1 = bwd
  const int b = blockIdx.x >> 5;
  const int s = blockIdx.x & 31;
  const int len = lengths[b];
  const int sL = s * SEGL;
  if (sL >= len) return;
  const int lenm1 = len - 1;
  const int tend = min(sL + SEGL, len);
  const int end = tend - 1;
  const int t1 = min(lenm1, end + BURN);   // bwd init row (beta == 1 there)

  const int dir = half ? -1 : 1;
  // cursor c = pot row consumed at step g (c = cst + dir*g)
  const int cst  = half ? (end + BURN) : ((s == 0) ? (1 - TRIPB) : (sL - BURN + 1));
  // steps with g < skip leave raw at its init value
  const int skip = half ? (end + BURN - t1) : ((s == 0) ? TRIPB : 0);
  const int wlo = sL;
  const int whi = half ? min(end, t1) : end;
  const unsigned uspan = (unsigned)(whi - wlo);

  // eT pairs: fwd lane j needs column j of exp(trans); bwd lane i needs row i.
  v2f eT2[16];
#pragma unroll
  for (int k = 0; k < 16; ++k) {
    const int i0 = 2 * k, i1 = 2 * k + 1;
    float ta = half ? trans[j * Nq + i0] : trans[i0 * Nq + j];
    float tb = half ? trans[j * Nq + i1] : trans[i1 * Nq + j];
    eT2[k].x = exp2f(ta * LOG2E);
    eT2[k].y = exp2f(tb * LOG2E);
  }

  const float* pb = pot + (size_t)b * Tq * Nq;
  const int rinit = half ? 0 : ((s == 0) ? 0 : sL - BURN);
  float raw = half ? 1.0f : exp2f(pb[rinit * Nq + j] * LOG2E);

  u16* outp = (half ? eaB : eaF) + (size_t)b * Tq * Nq + j
              + (ptrdiff_t)(cst - half) * Nq;

  int c = cst;
  float pn[UNR];
#pragma unroll
  for (int k = 0; k < UNR; ++k) {
    int cc = min(max(c + dir * k, 0), lenm1);
    pn[k] = pb[cc * Nq + j];
  }

  int gb = 0;
#pragma unroll 1
  for (int blk = 0; blk < NBLK; ++blk) {
    float pc[UNR];
#pragma unroll
    for (int k = 0; k < UNR; ++k) pc[k] = pn[k];
#pragma unroll
    for (int k = 0; k < UNR; ++k) {
      int cc = min(max(c + dir * (k + UNR), 0), lenm1);
      pn[k] = pb[cc * Nq + j];
    }
#pragma unroll
    for (int k = 0; k < UNR; ++k) {
      float epot = exp2f(pc[k] * LOG2E);
      float pre = half ? raw * epot : raw;
      sbuf[tid] = pre;
      v4f B0 = sbuf4[(half << 3) + 0];
      v4f B1 = sbuf4[(half << 3) + 1];
      v4f B2 = sbuf4[(half << 3) + 2];
      v4f B3 = sbuf4[(half << 3) + 3];
      v4f B4 = sbuf4[(half << 3) + 4];
      v4f B5 = sbuf4[(half << 3) + 5];
      v4f B6 = sbuf4[(half << 3) + 6];
      v4f B7 = sbuf4[(half << 3) + 7];
      // power-of-2 renorm factor from the half's first component
      int eb = __float_as_int(B0.x) & 0x7f800000;
      float corr = __int_as_float(0x7f000000 - eb);
      v2f p, a0, a1, a2, a3;
      p.x = B0.x; p.y = B0.y; a0 = p * eT2[0];
      p.x = B0.z; p.y = B0.w; a1 = p * eT2[1];
      p.x = B1.x; p.y = B1.y; a2 = p * eT2[2];
      p.x = B1.z; p.y = B1.w; a3 = p * eT2[3];
      p.x = B2.x; p.y = B2.y; a0 += p * eT2[4];
      p.x = B2.z; p.y = B2.w; a1 += p * eT2[5];
      p.x = B3.x; p.y = B3.y; a2 += p * eT2[6];
      p.x = B3.z; p.y = B3.w; a3 += p * eT2[7];
      p.x = B4.x; p.y = B4.y; a0 += p * eT2[8];
      p.x = B4.z; p.y = B4.w; a1 += p * eT2[9];
      p.x = B5.x; p.y = B5.y; a2 += p * eT2[10];
      p.x = B5.z; p.y = B5.w; a3 += p * eT2[11];
      p.x = B6.x; p.y = B6.y; a0 += p * eT2[12];
      p.x = B6.z; p.y = B6.w; a1 += p * eT2[13];
      p.x = B7.x; p.y = B7.y; a2 += p * eT2[14];
      p.x = B7.z; p.y = B7.w; a3 += p * eT2[15];
      v2f asum = (a0 + a1) + (a2 + a3);
      float hsum = asum.x + asum.y;
      float qc = corr * (half ? 1.0f : epot);
      float nr = hsum * qc;
      raw = ((gb + k) >= skip) ? nr : raw;
      int r = c - half;
      if ((unsigned)(r - wlo) <= uspan) *outp = f2bf(raw);
      outp += dir * Nq;
      c += dir;
    }
    gb += UNR;
  }
}

// One block per batch, 1024 threads, one THREAD per position.
// p_t[j] = a_j b_j / sum_j a_j b_j (per-row normalization — scale invariant),
// I = sum_t p_t[y_t]; sum_j p_t[j] == 1 so the dice denominator is 2*len.
extern "C" __global__ void __launch_bounds__(1024)
dice_kernel(const u16* __restrict__ eaF, const u16* __restrict__ eaB,
            const int* __restrict__ y, const int* __restrict__ lengths,
            float* __restrict__ out) {
  const int b = blockIdx.x;
  const int tid = threadIdx.x;
  const int len = lengths[b];
  const size_t base = (size_t)b * Tq;
  float I = 0.f;
#pragma unroll
  for (int q = 0; q < Tq / 1024; ++q) {
    int t = tid + q * 1024;
    if (t < len) {
      const u16* ar = eaF + (base + t) * Nq;
      const u16* br = eaB + (base + t) * Nq;
      const uint4* a4 = (const uint4*)ar;
      const uint4* b4 = (const uint4*)br;
      float c0 = 0.f, c1 = 0.f, c2 = 0.f, c3 = 0.f;
#pragma unroll
      for (int w = 0; w < 4; ++w) {
        uint4 ua = a4[w], ub = b4[w];
        c0 = fmaf(__uint_as_float(ua.x << 16), __uint_as_float(ub.x << 16), c0);
        c1 = fmaf(__uint_as_float(ua.x & 0xffff0000u), __uint_as_float(ub.x & 0xffff0000u), c1);
        c2 = fmaf(__uint_as_float(ua.y << 16), __uint_as_float(ub.y << 16), c2);
        c3 = fmaf(__uint_as_float(ua.y & 0xffff0000u), __uint_as_float(ub.y & 0xffff0000u), c3);
        c0 = fmaf(__uint_as_float(ua.z << 16), __uint_as_float(ub.z << 16), c0);
        c1 = fmaf(__uint_as_float(ua.z & 0xffff0000u), __uint_as_float(ub.z & 0xffff0000u), c1);
        c2 = fmaf(__uint_as_float(ua.w << 16), __uint_as_float(ub.w << 16), c2);
        c3 = fmaf(__uint_as_float(ua.w & 0xffff0000u), __uint_as_float(ub.w & 0xffff0000u), c3);
      }
      float v = (c0 + c1) + (c2 + c3);
      int yt = y[base + t];
      float ay = __uint_as_float(((unsigned)ar[yt]) << 16);
      float by = __uint_as_float(((unsigned)br[yt]) << 16);
      I += (ay * by) / v;
    }
  }
#pragma unroll
  for (int m = 1; m < 64; m <<= 1) I += __shfl_xor(I, m);
  __shared__ float sI[16];
  if ((tid & 63) == 0) sI[tid >> 6] = I;
  __syncthreads();
  if (tid == 0) {
    float It = 0.f;
#pragma unroll
    for (int k = 0; k < 16; ++k) It += sI[k];
    float dice = (2.f * It + 1.f) / (2.f * (float)len + 1.f);
    out[b] = 1.f - dice;
  }
}

extern "C" void kernel_launch(void* const* d_in, const int* in_sizes, int n_in,
                              void* d_out, int out_size, void* d_ws, size_t ws_size,
                              hipStream_t stream) {
  const float* pot = (const float*)d_in[0];
  const int* y_true = (const int*)d_in[1];
  const int* lengths = (const int*)d_in[2];
  const float* trans = (const float*)d_in[3];
  float* out = (float*)d_out;

  char* ws = (char*)d_ws;
  const size_t n_elems = (size_t)Bq * Tq * Nq;     // 16,777,216
  u16* eaF = (u16*)ws;                             // 32 MiB
  u16* eaB = (u16*)(ws + n_elems * 2);             // 32 MiB

  crf_chain_kernel<<<Bq * NSEG, 64, 0, stream>>>(pot, lengths, trans, eaF, eaB);
  dice_kernel<<<Bq, 1024, 0, stream>>>(eaF, eaB, y_true, lengths, out);
}